// Round 15
// baseline (251.686 us; speedup 1.0000x reference)
//
#include <hip/hip_runtime.h>
#include <hip/hip_bf16.h>
#include <math.h>

#define NAn 40000
#define NBn 40000
#define NEe 250000
#define Cc 128
#define Hh 4
#define Ll 2
static constexpr float INV_SQRT_D = 0.17677669529663687f; // 1/sqrt(32)
static constexpr float LOG2E = 1.4426950408889634f;

typedef __hip_bfloat16 bf16;
typedef unsigned short u16;
typedef unsigned int u32;
typedef short s16x8 __attribute__((ext_vector_type(8)));
typedef float f32x4 __attribute__((ext_vector_type(4)));
typedef float f32x2 __attribute__((ext_vector_type(2)));
typedef __bf16 bf16x2 __attribute__((ext_vector_type(2)));

#if defined(__has_builtin)
#  if __has_builtin(__builtin_amdgcn_fdot2_f32_bf16)
#    define HAVE_DOT2 1
#  endif
#endif
#ifndef HAVE_DOT2
#  define HAVE_DOT2 0
#endif

__device__ __forceinline__ float bf2f(bf16 x) { return __bfloat162float(x); }
__device__ __forceinline__ float lo_bf(u32 w) { return __uint_as_float(w << 16); }
__device__ __forceinline__ float hi_bf(u32 w) { return __uint_as_float(w & 0xffff0000u); }
__device__ __forceinline__ float ldf(const void* p, size_t i, int isb) {
    return isb ? bf2f(((const bf16*)p)[i]) : ((const float*)p)[i];
}
__device__ __forceinline__ u16 f2bu(float v) {
    union { bf16 b; u16 u; } c; c.b = __float2bfloat16(v); return c.u;
}
__device__ __forceinline__ float gelu_f(float v) {
    return 0.5f * v * (1.f + erff(v * 0.70710678118f));
}
__device__ __forceinline__ bf16x2 as_b2(u32 w) {
    union { u32 u; bf16x2 v; } c; c.u = w; return c.v;
}

// ---------------- dtype detection ----------------
__global__ void k_detect(const u16* __restrict__ x, int n, int* __restrict__ flag) {
    __shared__ float smax[256];
    int tid = threadIdx.x;
    float m = 0.f;
    for (int i = tid; i < n; i += 256) {
        float v = fabsf(__uint_as_float(((u32)x[i]) << 16));
        if (v != v) v = 1e30f;
        m = fmaxf(m, v);
    }
    smax[tid] = m;
    __syncthreads();
    for (int s = 128; s > 0; s >>= 1) {
        if (tid < s) smax[tid] = fmaxf(smax[tid], smax[tid + s]);
        __syncthreads();
    }
    if (tid == 0) flag[0] = (smax[0] > 1e4f) ? 0 : 1;
}

// ---------------- merged x-input convert ----------------
__global__ void k_convb(const void* __restrict__ xa, const void* __restrict__ xb,
                        bf16* __restrict__ da, bf16* __restrict__ db,
                        const int* __restrict__ dflag) {
    int isb = dflag[0];
    int i = blockIdx.x * 256 + threadIdx.x;
    int na = NAn * 64;
    if (i < na) da[i] = isb ? ((const bf16*)xa)[i] : __float2bfloat16(((const float*)xa)[i]);
    else if (i < na + NBn * 32) {
        int j = i - na;
        db[j] = isb ? ((const bf16*)xb)[j] : __float2bfloat16(((const float*)xb)[j]);
    }
}

// ---------------- merged small weight prep (384 threads) + deg zeroing ----------------
__global__ void k_prep_small(const void* __restrict__ lin_a_w, const void* __restrict__ lin_a_b,
                             const void* __restrict__ lin_b_w, const void* __restrict__ lin_b_b,
                             const void* __restrict__ a_lin_w, const void* __restrict__ a_lin_b,
                             const void* __restrict__ k_b, const void* __restrict__ q_b,
                             const void* __restrict__ v_b, const void* __restrict__ a_rel,
                             const void* __restrict__ m_rel, const void* __restrict__ p_rel,
                             float* __restrict__ bias_lin, bf16* __restrict__ wt_lin_a,
                             bf16* __restrict__ wt_lin_b, bf16* __restrict__ wt_alin,
                             float* __restrict__ b_kqv, int* __restrict__ deg,
                             const int* __restrict__ dflag) {
    int isb = dflag[0];
    int b = blockIdx.x, t = threadIdx.x;
    int z = b * 384 + t;
    if (z < 2 * NAn) deg[z] = 0;
    if (b < 2) {
        int i = b * 384 + t;
        if (i < 768) {
            float v = (i < 128) ? ldf(lin_a_b, i, isb)
                    : (i < 256) ? ldf(lin_b_b, i - 128, isb)
                                : ldf(a_lin_b, i - 256, isb);
            bias_lin[i] = v;
        }
    } else if (b < 205) {
        int e = (b - 2) * 384 + t;
        if (e < 8192) {            // wt_lin_a [128][64]
            int n = e >> 6, k = e & 63;
            wt_lin_a[e] = __float2bfloat16(ldf(lin_a_w, (size_t)k * 128 + n, isb));
        } else if (e < 12288) {    // wt_lin_b [128][32]
            int r = e - 8192; int n = r >> 5, k = r & 31;
            wt_lin_b[r] = __float2bfloat16(ldf(lin_b_w, (size_t)k * 128 + n, isb));
        } else if (e < 77824) {    // wt_alin [4][128][128]
            int r = e - 12288; int s = r >> 14, rem = r & 16383;
            int n = rem >> 7, k = rem & 127;
            wt_alin[r] = __float2bfloat16(ldf(a_lin_w, (size_t)s * 16384 + (size_t)k * 128 + n, isb));
        }
    } else {                       // kqv bias, lt = b-205; layout [k|v|q]; k scaled by LOG2E
        int lt = b - 205, j = t;
        float out;
        if (j < 128) {
            int h = j >> 5, e = j & 31;
            float s = ldf(p_rel, lt * Hh + h, isb) * INV_SQRT_D * LOG2E;
            float sum = 0.f;
            size_t kb0 = (size_t)lt * 128 + h * 32;
            size_t ar0 = ((size_t)lt * Hh + h) * 1024 + e;
            #pragma unroll
            for (int d = 0; d < 32; ++d) sum += ldf(k_b, kb0 + d, isb) * ldf(a_rel, ar0 + d * 32, isb);
            out = sum * s;
        } else if (j < 256) {
            int jj = j - 128; int h = jj >> 5, e = jj & 31;
            float sum = 0.f;
            size_t vb0 = (size_t)lt * 128 + h * 32;
            size_t mr0 = ((size_t)lt * Hh + h) * 1024 + e;
            #pragma unroll
            for (int d = 0; d < 32; ++d) sum += ldf(v_b, vb0 + d, isb) * ldf(m_rel, mr0 + d * 32, isb);
            out = sum;
        } else {
            out = ldf(q_b, (size_t)lt * 128 + (j - 256), isb);
        }
        b_kqv[(size_t)lt * 384 + j] = out;
    }
}

// ---------------- fused KQV weight prep: Wt[lt][384][128] bf16, layout [k|v|q] ----------------
__global__ void k_prep_kqv_w(const void* __restrict__ k_w, const void* __restrict__ q_w,
                             const void* __restrict__ v_w, const void* __restrict__ a_rel,
                             const void* __restrict__ m_rel, const void* __restrict__ p_rel,
                             bf16* __restrict__ Wt, const int* __restrict__ dflag) {
    int isb = dflag[0];
    int b = blockIdx.x;          // lt*128 + c (c = K index)
    int lt = b >> 7, c = b & 127;
    int j = threadIdx.x;         // 0..383 (N index)
    float out;
    if (j < 128) {               // k' scaled by p_rel/sqrt(D)*log2(e)
        int h = j >> 5, e = j & 31;
        float s = ldf(p_rel, lt * Hh + h, isb) * INV_SQRT_D * LOG2E;
        float sum = 0.f;
        size_t kw0 = ((size_t)lt * 128 + c) * 128 + h * 32;
        size_t ar0 = ((size_t)lt * Hh + h) * 1024 + e;
        #pragma unroll
        for (int d = 0; d < 32; ++d) sum += ldf(k_w, kw0 + d, isb) * ldf(a_rel, ar0 + d * 32, isb);
        out = sum * s;
    } else if (j < 256) {        // v'
        int jj = j - 128; int h = jj >> 5, e = jj & 31;
        float sum = 0.f;
        size_t vw0 = ((size_t)lt * 128 + c) * 128 + h * 32;
        size_t mr0 = ((size_t)lt * Hh + h) * 1024 + e;
        #pragma unroll
        for (int d = 0; d < 32; ++d) sum += ldf(v_w, vw0 + d, isb) * ldf(m_rel, mr0 + d * 32, isb);
        out = sum;
    } else {                     // q
        out = ldf(q_w, ((size_t)lt * 128 + c) * 128 + (j - 256), isb);
    }
    Wt[((size_t)lt * 384 + j) * 128 + c] = __float2bfloat16(out);
}

// ---------------- CSR build (both directions per launch) ----------------
__global__ void k_hist(const int* __restrict__ d0, const int* __restrict__ d1,
                       int* __restrict__ deg0, int* __restrict__ deg1) {
    int i = blockIdx.x * 256 + threadIdx.x;
    if (i >= NEe) return;
    if (blockIdx.y == 0) atomicAdd(&deg0[d0[i]], 1);
    else                 atomicAdd(&deg1[d1[i]], 1);
}

__global__ void k_scanA(const int* __restrict__ deg0, const int* __restrict__ deg1,
                        int* __restrict__ ex0, int* __restrict__ ex1,
                        int* __restrict__ bs0, int* __restrict__ bs1, int n) {
    const int* deg = blockIdx.y ? deg1 : deg0;
    int* excl = blockIdx.y ? ex1 : ex0;
    int* bsum = blockIdx.y ? bs1 : bs0;
    __shared__ int buf[256];
    int tid = threadIdx.x;
    int i = blockIdx.x * 256 + tid;
    int v = (i < n) ? deg[i] : 0;
    buf[tid] = v;
    __syncthreads();
    for (int off = 1; off < 256; off <<= 1) {
        int u = (tid >= off) ? buf[tid - off] : 0;
        __syncthreads();
        buf[tid] += u;
        __syncthreads();
    }
    int incl = buf[tid];
    if (i < n) excl[i] = incl - v;
    if (tid == 255) bsum[blockIdx.x] = incl;
}

__global__ void k_scanB(int* __restrict__ bs0, int* __restrict__ bs1, int nb) {
    int* bsum = blockIdx.x ? bs1 : bs0;
    __shared__ int buf[256];
    int tid = threadIdx.x;
    int v = (tid < nb) ? bsum[tid] : 0;
    buf[tid] = v;
    __syncthreads();
    for (int off = 1; off < 256; off <<= 1) {
        int u = (tid >= off) ? buf[tid - off] : 0;
        __syncthreads();
        buf[tid] += u;
        __syncthreads();
    }
    if (tid < nb) bsum[tid] = buf[tid] - v;
}

__global__ void k_scanC(int* __restrict__ rp0, int* __restrict__ rp1,
                        const int* __restrict__ bs0, const int* __restrict__ bs1,
                        int* __restrict__ cur0, int* __restrict__ cur1, int n) {
    int* rowptr = blockIdx.y ? rp1 : rp0;
    const int* bsum = blockIdx.y ? bs1 : bs0;
    int* cursor = blockIdx.y ? cur1 : cur0;
    int i = blockIdx.x * 256 + threadIdx.x;
    if (i < n) {
        int v = rowptr[i] + bsum[i >> 8];
        rowptr[i] = v;
        cursor[i] = v;
    }
    if (i == 0) rowptr[n] = NEe;
}

__global__ void k_scatter(const int* __restrict__ e0, const int* __restrict__ e1,
                          int* __restrict__ cur0, int* __restrict__ cur1,
                          int* __restrict__ cs0, int* __restrict__ cs1) {
    int i = blockIdx.x * 256 + threadIdx.x;
    if (i >= NEe) return;
    const int* e = blockIdx.y ? e1 : e0;
    int* cursor = blockIdx.y ? cur1 : cur0;
    int* csr = blockIdx.y ? cs1 : cs0;
    int d = e[NEe + i];
    int p = atomicAdd(&cursor[d], 1);
    csr[p] = e[i];
}

// ---------------- LDS-staged MFMA GEMM (unchanged from R14) ----------------
template <int KK, int EPI>
__global__ __launch_bounds__(256) void k_mmL(const bf16* __restrict__ A0, const bf16* __restrict__ A1,
                                             int lda,
                                             const bf16* __restrict__ W0, const bf16* __restrict__ W1,
                                             const float* __restrict__ bias0, const float* __restrict__ bias1,
                                             bf16* __restrict__ out0, bf16* __restrict__ out1, int ldo,
                                             const bf16* __restrict__ old0, const bf16* __restrict__ old1,
                                             const void* __restrict__ skipp, int si0, int si1,
                                             const int* __restrict__ dflag) {
    constexpr int NK = KK / 32;
    constexpr int GPR = KK / 8;
    constexpr int SG = GPR + 1;
    __shared__ u16 ldsA[64 * SG * 8];
    __shared__ u16 ldsB[128 * SG * 8];

    int z = blockIdx.z;
    const bf16* A = z ? A1 : A0;
    const bf16* Wt = z ? W1 : W0;
    const float* bias = z ? bias1 : bias0;
    bf16* out = z ? out1 : out0;
    const bf16* oldx = z ? old1 : old0;
    int skip_idx = z ? si1 : si0;

    int tid = threadIdx.x;
    int r0 = blockIdx.x * 64;
    int n0 = blockIdx.y * 128;

    #pragma unroll
    for (int i = 0; i < 64 * GPR / 256; ++i) {
        int idx = tid + i * 256;
        int row = idx / GPR, g = idx % GPR;
        uint4 v = *(const uint4*)(A + (size_t)(r0 + row) * lda + g * 8);
        *(uint4*)&ldsA[(row * SG + g) * 8] = v;
    }
    #pragma unroll
    for (int i = 0; i < 128 * GPR / 256; ++i) {
        int idx = tid + i * 256;
        int row = idx / GPR, g = idx % GPR;
        uint4 v = *(const uint4*)(Wt + (size_t)(n0 + row) * KK + g * 8);
        *(uint4*)&ldsB[(row * SG + g) * 8] = v;
    }
    __syncthreads();

    int w = tid >> 6, l = tid & 63;
    int wr0 = (w & 1) * 32;
    int wc0 = (w >> 1) * 64;
    int lr = l & 15, kb = l >> 4;

    s16x8 af[2][NK];
    #pragma unroll
    for (int mt = 0; mt < 2; ++mt)
        #pragma unroll
        for (int kf = 0; kf < NK; ++kf) {
            int row = wr0 + mt * 16 + lr;
            af[mt][kf] = *(const s16x8*)&ldsA[(row * SG + kf * 4 + kb) * 8];
        }
    s16x8 bfr[4][NK];
    #pragma unroll
    for (int nt = 0; nt < 4; ++nt)
        #pragma unroll
        for (int kf = 0; kf < NK; ++kf) {
            int row = wc0 + nt * 16 + lr;
            bfr[nt][kf] = *(const s16x8*)&ldsB[(row * SG + kf * 4 + kb) * 8];
        }

    f32x4 acc[2][4] = {};
    #pragma unroll
    for (int kf = 0; kf < NK; ++kf)
        #pragma unroll
        for (int mt = 0; mt < 2; ++mt)
            #pragma unroll
            for (int nt = 0; nt < 4; ++nt)
                acc[mt][nt] = __builtin_amdgcn_mfma_f32_16x16x32_bf16(
                    af[mt][kf], bfr[nt][kf], acc[mt][nt], 0, 0, 0);

    float sg = 0.f;
    if (EPI == 2) {
        float sv = ldf(skipp, skip_idx, dflag[0]);
        sg = 1.f / (1.f + expf(-sv));
    }
    #pragma unroll
    for (int mt = 0; mt < 2; ++mt)
        #pragma unroll
        for (int nt = 0; nt < 4; ++nt) {
            int col = n0 + wc0 + nt * 16 + lr;
            float bv = bias[col];
            #pragma unroll
            for (int r = 0; r < 4; ++r) {
                int row = r0 + wr0 + mt * 16 + kb * 4 + r;
                float o = acc[mt][nt][r] + bv;
                if (EPI == 1) o = fmaxf(o, 0.f);
                if (EPI == 2) o = sg * o + (1.f - sg) * bf2f(oldx[(size_t)row * 128 + col]);
                out[(size_t)row * ldo + col] = __float2bfloat16(o);
            }
        }
}

// ---------------- fused edge aggregation v5: 4 edges in flight / node ----------------
// Block = 4 waves = 8 nodes (2/wave). Per node: 32 lanes, eg = (l5>>3) in 0..3
// (4 e-groups), hp = l5&7 covers cols [hp*16, hp*16+16). Head = hp>>1; dot-reduce
// is one shfl_xor(1). Epilogue: 2-round butterfly reduce-scatter (xor16, xor8) ->
// lane (eg,hp) stores cols hp*16 + 4*eg .. +3. kqv layout [k|v|q]; k' pre-scaled
// by log2(e); writes gelu(attn) into q-cols.
__global__ __launch_bounds__(256) void k_edge(const bf16* __restrict__ kv0, bf16* __restrict__ qm0,
                                              const int* __restrict__ rp0, const int* __restrict__ cs0,
                                              const bf16* __restrict__ kv1, bf16* __restrict__ qm1,
                                              const int* __restrict__ rp1, const int* __restrict__ cs1,
                                              int nblk0) {
    int dir = (blockIdx.x >= nblk0);
    int blk = dir ? (blockIdx.x - nblk0) : blockIdx.x;
    const bf16* kv = dir ? kv1 : kv0;
    bf16* qm = dir ? qm1 : qm0;
    const int* rowptr = dir ? rp1 : rp0;
    const int* csr = dir ? cs1 : cs0;

    int tid = threadIdx.x;
    int n = blk * 8 + (tid >> 5);       // node index (8 per block, 2 per wave)
    int l5 = tid & 31;
    int eg = l5 >> 3, hp = l5 & 7;
    bf16* qrow = qm + (size_t)n * 384 + 256;

    uint4 qv0 = *(const uint4*)(qrow + hp * 16);
    uint4 qv1 = *(const uint4*)(qrow + hp * 16 + 8);
#if HAVE_DOT2
    bf16x2 qb0 = as_b2(qv0.x), qb1 = as_b2(qv0.y), qb2 = as_b2(qv0.z), qb3 = as_b2(qv0.w);
    bf16x2 qb4 = as_b2(qv1.x), qb5 = as_b2(qv1.y), qb6 = as_b2(qv1.z), qb7 = as_b2(qv1.w);
#else
    float qf0 = lo_bf(qv0.x), qf1 = hi_bf(qv0.x), qf2 = lo_bf(qv0.y), qf3 = hi_bf(qv0.y);
    float qf4 = lo_bf(qv0.z), qf5 = hi_bf(qv0.z), qf6 = lo_bf(qv0.w), qf7 = hi_bf(qv0.w);
    float qf8 = lo_bf(qv1.x), qf9 = hi_bf(qv1.x), qfa = lo_bf(qv1.y), qfb = hi_bf(qv1.y);
    float qfc = lo_bf(qv1.z), qfd = hi_bf(qv1.z), qfe = lo_bf(qv1.w), qff = hi_bf(qv1.w);
#endif

    float den = 0.f;
    f32x2 a0 = {0.f,0.f}, a1 = {0.f,0.f}, a2 = {0.f,0.f}, a3 = {0.f,0.f};
    f32x2 a4 = {0.f,0.f}, a5 = {0.f,0.f}, a6 = {0.f,0.f}, a7 = {0.f,0.f};
    int e0 = rowptr[n], e1 = rowptr[n + 1];
    int sidx_n = 0;
    {
        int ee = e0 + eg;
        if (ee < e1) sidx_n = csr[ee];
    }
    for (int e = e0; e < e1; e += 4) {
        int sidx = sidx_n;
        bool valid = (e + eg) < e1;
        int en = e + 4 + eg;
        if (en < e1) sidx_n = csr[en];     // prefetch next iteration's index
        const bf16* row = kv + (size_t)sidx * 384;
        uint4 kw0 = *(const uint4*)(row + hp * 16);
        uint4 kw1 = *(const uint4*)(row + hp * 16 + 8);
        uint4 vw0 = *(const uint4*)(row + 128 + hp * 16);
        uint4 vw1 = *(const uint4*)(row + 128 + hp * 16 + 8);
#if HAVE_DOT2
        float part = __builtin_amdgcn_fdot2_f32_bf16(as_b2(kw0.x), qb0, 0.f, false);
        part = __builtin_amdgcn_fdot2_f32_bf16(as_b2(kw0.y), qb1, part, false);
        part = __builtin_amdgcn_fdot2_f32_bf16(as_b2(kw0.z), qb2, part, false);
        part = __builtin_amdgcn_fdot2_f32_bf16(as_b2(kw0.w), qb3, part, false);
        part = __builtin_amdgcn_fdot2_f32_bf16(as_b2(kw1.x), qb4, part, false);
        part = __builtin_amdgcn_fdot2_f32_bf16(as_b2(kw1.y), qb5, part, false);
        part = __builtin_amdgcn_fdot2_f32_bf16(as_b2(kw1.z), qb6, part, false);
        part = __builtin_amdgcn_fdot2_f32_bf16(as_b2(kw1.w), qb7, part, false);
#else
        float part = qf0 * lo_bf(kw0.x) + qf1 * hi_bf(kw0.x)
                   + qf2 * lo_bf(kw0.y) + qf3 * hi_bf(kw0.y)
                   + qf4 * lo_bf(kw0.z) + qf5 * hi_bf(kw0.z)
                   + qf6 * lo_bf(kw0.w) + qf7 * hi_bf(kw0.w)
                   + qf8 * lo_bf(kw1.x) + qf9 * hi_bf(kw1.x)
                   + qfa * lo_bf(kw1.y) + qfb * hi_bf(kw1.y)
                   + qfc * lo_bf(kw1.z) + qfd * hi_bf(kw1.z)
                   + qfe * lo_bf(kw1.w) + qff * hi_bf(kw1.w);
#endif
        part += __shfl_xor(part, 1);       // head = hp>>1: 2 lanes per head
        float wgt = valid ? exp2f(part) : 0.f;
        den += wgt;
        f32x2 w2; w2[0] = wgt; w2[1] = wgt;
        f32x2 t;
        t[0] = lo_bf(vw0.x); t[1] = hi_bf(vw0.x); a0 += w2 * t;
        t[0] = lo_bf(vw0.y); t[1] = hi_bf(vw0.y); a1 += w2 * t;
        t[0] = lo_bf(vw0.z); t[1] = hi_bf(vw0.z); a2 += w2 * t;
        t[0] = lo_bf(vw0.w); t[1] = hi_bf(vw0.w); a3 += w2 * t;
        t[0] = lo_bf(vw1.x); t[1] = hi_bf(vw1.x); a4 += w2 * t;
        t[0] = lo_bf(vw1.y); t[1] = hi_bf(vw1.y); a5 += w2 * t;
        t[0] = lo_bf(vw1.z); t[1] = hi_bf(vw1.z); a6 += w2 * t;
        t[0] = lo_bf(vw1.w); t[1] = hi_bf(vw1.w); a7 += w2 * t;
    }
    // den: sum over 4 e-groups (eg bits are l5 bits 3,4)
    den += __shfl_xor(den, 8);
    den += __shfl_xor(den, 16);
    // reduce-scatter accumulators over e-groups.
    // Round 1 (xor 16, eg bit1): egs {0,1} own pairs 0..3, egs {2,3} own pairs 4..7.
    bool keepLo = (eg < 2);
    f32x2 s0 = keepLo ? a4 : a0;
    f32x2 s1 = keepLo ? a5 : a1;
    f32x2 s2 = keepLo ? a6 : a2;
    f32x2 s3 = keepLo ? a7 : a3;
    f32x2 r0v, r1v, r2v, r3v;
    r0v[0] = __shfl_xor(s0[0], 16); r0v[1] = __shfl_xor(s0[1], 16);
    r1v[0] = __shfl_xor(s1[0], 16); r1v[1] = __shfl_xor(s1[1], 16);
    r2v[0] = __shfl_xor(s2[0], 16); r2v[1] = __shfl_xor(s2[1], 16);
    r3v[0] = __shfl_xor(s3[0], 16); r3v[1] = __shfl_xor(s3[1], 16);
    f32x2 b0 = (keepLo ? a0 : a4) + r0v;
    f32x2 b1 = (keepLo ? a1 : a5) + r1v;
    f32x2 b2 = (keepLo ? a2 : a6) + r2v;
    f32x2 b3 = (keepLo ? a3 : a7) + r3v;
    // Round 2 (xor 8, eg bit0): even egs own first 2 pairs (b0,b1), odd own (b2,b3).
    bool keep2 = !(eg & 1);
    f32x2 t0 = keep2 ? b2 : b0;
    f32x2 t1 = keep2 ? b3 : b1;
    f32x2 u0, u1;
    u0[0] = __shfl_xor(t0[0], 8); u0[1] = __shfl_xor(t0[1], 8);
    u1[0] = __shfl_xor(t1[0], 8); u1[1] = __shfl_xor(t1[1], 8);
    f32x2 c0 = (keep2 ? b0 : b2) + u0;   // cols hp*16 + 4*eg + 0,1
    f32x2 c1 = (keep2 ? b1 : b3) + u1;   // cols hp*16 + 4*eg + 2,3
    float inv = 1.f / (den + 1e-16f);
    u32 p0 = (u32)f2bu(gelu_f(c0[0] * inv)) | ((u32)f2bu(gelu_f(c0[1] * inv)) << 16);
    u32 p1 = (u32)f2bu(gelu_f(c1[0] * inv)) | ((u32)f2bu(gelu_f(c1[1] * inv)) << 16);
    uint2 st; st.x = p0; st.y = p1;
    *(uint2*)(qrow + hp * 16 + 4 * eg) = st;
}

// ---------------- final output (adaptive dtype), vectorized 8 elems/thread ----------------
__global__ void k_out(const bf16* __restrict__ xa, const bf16* __restrict__ xb,
                      void* __restrict__ out, const int* __restrict__ dflag) {
    int isb = dflag[0];
    int i = blockIdx.x * 256 + threadIdx.x;   // 8-elem group index
    int na8 = NAn * Cc / 8;
    if (i >= 2 * na8) return;
    const bf16* src = (i < na8) ? xa : xb;
    int j = (i < na8) ? i : i - na8;
    uint4 v = *(const uint4*)(src + (size_t)j * 8);
    if (isb) {
        ((uint4*)out)[i] = v;
    } else {
        float4 f0 = make_float4(lo_bf(v.x), hi_bf(v.x), lo_bf(v.y), hi_bf(v.y));
        float4 f1 = make_float4(lo_bf(v.z), hi_bf(v.z), lo_bf(v.w), hi_bf(v.w));
        ((float4*)out)[i * 2] = f0;
        ((float4*)out)[i * 2 + 1] = f1;
    }
}

extern "C" void kernel_launch(void* const* d_in, const int* in_sizes, int n_in,
                              void* d_out, int out_size, void* d_ws, size_t ws_size,
                              hipStream_t stream) {
    const void* x_a     = d_in[0];
    const void* x_b     = d_in[1];
    const int*  edge_ab = (const int*)d_in[2];
    const int*  edge_ba = (const int*)d_in[3];
    const void* lin_a_w = d_in[4];
    const void* lin_a_b = d_in[5];
    const void* lin_b_w = d_in[6];
    const void* lin_b_b = d_in[7];
    const void* k_w     = d_in[8];
    const void* k_b     = d_in[9];
    const void* q_w     = d_in[10];
    const void* q_b     = d_in[11];
    const void* v_w     = d_in[12];
    const void* v_b     = d_in[13];
    const void* a_rel   = d_in[14];
    const void* m_rel   = d_in[15];
    const void* p_rel   = d_in[16];
    const void* a_lin_w = d_in[17];
    const void* a_lin_b = d_in[18];
    const void* skip    = d_in[19];

    // -------- workspace layout --------
    char* p = (char*)d_ws;
    auto falloc = [&](size_t n) { float* r = (float*)p; p += n * sizeof(float); return r; };
    float* bias_lin = falloc(768);       // [lin_a_b | lin_b_b | a_lin_b(512)]
    float* b_kqv    = falloc(4 * 384);
    auto halloc = [&](size_t n) { bf16* r = (bf16*)p; p += n * sizeof(bf16); return r; };
    bf16* x_a_bf   = halloc((size_t)NAn * 64);
    bf16* x_b_bf   = halloc((size_t)NBn * 32);
    bf16* xa_bf    = halloc((size_t)NAn * Cc);
    bf16* xb_bf    = halloc((size_t)NBn * Cc);
    bf16* kqv_a    = halloc((size_t)NAn * 384);
    bf16* kqv_b    = halloc((size_t)NBn * 384);
    bf16* wt_lin_a = halloc(128 * 64);
    bf16* wt_lin_b = halloc(128 * 32);
    bf16* wt_kqv   = halloc(4 * 384 * 128);
    bf16* wt_alin  = halloc(4 * 128 * 128);
    auto ialloc = [&](size_t n) { int* r = (int*)p; p += n * sizeof(int); return r; };
    int* dflag     = ialloc(4);
    int* rowptr_ab = ialloc(NBn + 1);
    int* rowptr_ba = ialloc(NAn + 1);
    int* deg_ab    = ialloc(NBn);       // deg_ab/deg_ba adjacent -> zeroed by k_prep_small
    int* deg_ba    = ialloc(NAn);
    int* cursor_ab = ialloc(NBn);
    int* cursor_ba = ialloc(NAn);
    int* bsum_ab   = ialloc(256);
    int* bsum_ba   = ialloc(256);
    int* csr_ab    = ialloc(NEe);
    int* csr_ba    = ialloc(NEe);

    // -------- dtype detection --------
    k_detect<<<1, 256, 0, stream>>>((const u16*)x_a, 8192, dflag);

    // -------- weight prep (2 launches; prep_small also zeros deg) --------
    k_prep_small<<<209, 384, 0, stream>>>(lin_a_w, lin_a_b, lin_b_w, lin_b_b, a_lin_w, a_lin_b,
                                          k_b, q_b, v_b, a_rel, m_rel, p_rel,
                                          bias_lin, wt_lin_a, wt_lin_b, wt_alin, b_kqv,
                                          deg_ab, dflag);
    k_prep_kqv_w<<<512, 384, 0, stream>>>(k_w, q_w, v_w, a_rel, m_rel, p_rel, wt_kqv, dflag);

    // -------- x inputs -> bf16 --------
    k_convb<<<(NAn * 64 + NBn * 32 + 255) / 256, 256, 0, stream>>>(x_a, x_b, x_a_bf, x_b_bf, dflag);

    // -------- CSR build, both directions --------
    dim3 eg((NEe + 255) / 256, 2);
    k_hist<<<eg, 256, 0, stream>>>(edge_ab + NEe, edge_ba + NEe, deg_ab, deg_ba);
    int nblk = (NBn + 255) / 256; // 157
    k_scanA<<<dim3(nblk, 2), 256, 0, stream>>>(deg_ab, deg_ba, rowptr_ab, rowptr_ba,
                                               bsum_ab, bsum_ba, NBn);
    k_scanB<<<2, 256, 0, stream>>>(bsum_ab, bsum_ba, nblk);
    k_scanC<<<dim3(nblk, 2), 256, 0, stream>>>(rowptr_ab, rowptr_ba, bsum_ab, bsum_ba,
                                               cursor_ab, cursor_ba, NBn);
    k_scatter<<<eg, 256, 0, stream>>>(edge_ab, edge_ba, cursor_ab, cursor_ba, csr_ab, csr_ba);

    // -------- input linears + relu (LDS-staged) --------
    k_mmL<64, 1><<<dim3(NAn / 64, 1, 1), 256, 0, stream>>>(
        x_a_bf, x_a_bf, 64, wt_lin_a, wt_lin_a, bias_lin, bias_lin,
        xa_bf, xa_bf, 128, nullptr, nullptr, nullptr, 0, 0, dflag);
    k_mmL<32, 1><<<dim3(NBn / 64, 1, 1), 256, 0, stream>>>(
        x_b_bf, x_b_bf, 32, wt_lin_b, wt_lin_b, bias_lin + 128, bias_lin + 128,
        xb_bf, xb_bf, 128, nullptr, nullptr, nullptr, 0, 0, dflag);

    // -------- layers --------
    for (int l = 0; l < Ll; ++l) {
        int lt0 = l * 2 + 0, lt1 = l * 2 + 1;
        // kqv: LDS-staged, grid (625, 3, 2)
        k_mmL<128, 0><<<dim3(NAn / 64, 3, 2), 256, 0, stream>>>(
            xa_bf, xb_bf, 128,
            wt_kqv + (size_t)lt0 * 384 * 128, wt_kqv + (size_t)lt1 * 384 * 128,
            b_kqv + (size_t)lt0 * 384, b_kqv + (size_t)lt1 * 384,
            kqv_a, kqv_b, 384, nullptr, nullptr, nullptr, 0, 0, dflag);
        int nblk0 = NBn / 8; // 5000 blocks per direction, 8 nodes/block
        k_edge<<<nblk0 + NAn / 8, 256, 0, stream>>>(
            kqv_a, kqv_b, rowptr_ab, csr_ab,
            kqv_b, kqv_a, rowptr_ba, csr_ba, nblk0);
        // a_lin + skip blend (LDS-staged, in-place update of xa_bf/xb_bf)
        k_mmL<128, 2><<<dim3(NAn / 64, 1, 2), 256, 0, stream>>>(
            kqv_a + 256, kqv_b + 256, 384,
            wt_alin + (size_t)lt0 * 128 * 128, wt_alin + (size_t)lt1 * 128 * 128,
            bias_lin + 256 + (size_t)lt0 * 128, bias_lin + 256 + (size_t)lt1 * 128,
            xa_bf, xb_bf, 128, xa_bf, xb_bf, skip, lt0, lt1, dflag);
    }

    // -------- output --------
    k_out<<<(2 * NAn * Cc / 8 + 255) / 256, 256, 0, stream>>>(xa_bf, xb_bf, d_out, dflag);
}

// Round 16
// 247.130 us; speedup vs baseline: 1.0184x; 1.0184x over previous
//
#include <hip/hip_runtime.h>
#include <hip/hip_bf16.h>
#include <math.h>

#define NAn 40000
#define NBn 40000
#define NEe 250000
#define Cc 128
#define Hh 4
#define Ll 2
static constexpr float INV_SQRT_D = 0.17677669529663687f; // 1/sqrt(32)
static constexpr float LOG2E = 1.4426950408889634f;

typedef __hip_bfloat16 bf16;
typedef unsigned short u16;
typedef unsigned int u32;
typedef short s16x8 __attribute__((ext_vector_type(8)));
typedef float f32x4 __attribute__((ext_vector_type(4)));
typedef float f32x2 __attribute__((ext_vector_type(2)));
typedef __bf16 bf16x2 __attribute__((ext_vector_type(2)));

#if defined(__has_builtin)
#  if __has_builtin(__builtin_amdgcn_fdot2_f32_bf16)
#    define HAVE_DOT2 1
#  endif
#endif
#ifndef HAVE_DOT2
#  define HAVE_DOT2 0
#endif

__device__ __forceinline__ float bf2f(bf16 x) { return __bfloat162float(x); }
__device__ __forceinline__ float lo_bf(u32 w) { return __uint_as_float(w << 16); }
__device__ __forceinline__ float hi_bf(u32 w) { return __uint_as_float(w & 0xffff0000u); }
__device__ __forceinline__ float ldf(const void* p, size_t i, int isb) {
    return isb ? bf2f(((const bf16*)p)[i]) : ((const float*)p)[i];
}
__device__ __forceinline__ u16 f2bu(float v) {
    union { bf16 b; u16 u; } c; c.b = __float2bfloat16(v); return c.u;
}
__device__ __forceinline__ float gelu_f(float v) {
    return 0.5f * v * (1.f + erff(v * 0.70710678118f));
}
__device__ __forceinline__ bf16x2 as_b2(u32 w) {
    union { u32 u; bf16x2 v; } c; c.u = w; return c.v;
}

// ---------------- dtype detection ----------------
__global__ void k_detect(const u16* __restrict__ x, int n, int* __restrict__ flag) {
    __shared__ float smax[256];
    int tid = threadIdx.x;
    float m = 0.f;
    for (int i = tid; i < n; i += 256) {
        float v = fabsf(__uint_as_float(((u32)x[i]) << 16));
        if (v != v) v = 1e30f;
        m = fmaxf(m, v);
    }
    smax[tid] = m;
    __syncthreads();
    for (int s = 128; s > 0; s >>= 1) {
        if (tid < s) smax[tid] = fmaxf(smax[tid], smax[tid + s]);
        __syncthreads();
    }
    if (tid == 0) flag[0] = (smax[0] > 1e4f) ? 0 : 1;
}

// ---------------- merged x-input convert (vectorized, 8 elems/thread) ----------------
__global__ void k_convb(const void* __restrict__ xa, const void* __restrict__ xb,
                        bf16* __restrict__ da, bf16* __restrict__ db,
                        const int* __restrict__ dflag) {
    int isb = dflag[0];
    int t = blockIdx.x * 256 + threadIdx.x;   // 8-elem group index
    int na8 = NAn * 64 / 8;
    const void* src; bf16* dst; int j;
    if (t < na8) { src = xa; dst = da; j = t; }
    else {
        j = t - na8;
        if (j >= NBn * 32 / 8) return;
        src = xb; dst = db;
    }
    if (isb) {
        *(uint4*)(dst + (size_t)j * 8) = ((const uint4*)src)[j];
    } else {
        const float* s = (const float*)src;
        union { u16 o[8]; uint4 v; } pk;
        #pragma unroll
        for (int i = 0; i < 8; ++i) pk.o[i] = f2bu(s[(size_t)j * 8 + i]);
        *(uint4*)(dst + (size_t)j * 8) = pk.v;
    }
}

// ---------------- merged small weight prep (384 threads) + deg zeroing ----------------
__global__ void k_prep_small(const void* __restrict__ lin_a_w, const void* __restrict__ lin_a_b,
                             const void* __restrict__ lin_b_w, const void* __restrict__ lin_b_b,
                             const void* __restrict__ a_lin_w, const void* __restrict__ a_lin_b,
                             const void* __restrict__ k_b, const void* __restrict__ q_b,
                             const void* __restrict__ v_b, const void* __restrict__ a_rel,
                             const void* __restrict__ m_rel, const void* __restrict__ p_rel,
                             float* __restrict__ bias_lin, bf16* __restrict__ wt_lin_a,
                             bf16* __restrict__ wt_lin_b, bf16* __restrict__ wt_alin,
                             float* __restrict__ b_kqv, int* __restrict__ deg,
                             const int* __restrict__ dflag) {
    int isb = dflag[0];
    int b = blockIdx.x, t = threadIdx.x;
    int z = b * 384 + t;
    if (z < 2 * NAn) deg[z] = 0;
    if (b < 2) {
        int i = b * 384 + t;
        if (i < 768) {
            float v = (i < 128) ? ldf(lin_a_b, i, isb)
                    : (i < 256) ? ldf(lin_b_b, i - 128, isb)
                                : ldf(a_lin_b, i - 256, isb);
            bias_lin[i] = v;
        }
    } else if (b < 205) {
        int e = (b - 2) * 384 + t;
        if (e < 8192) {            // wt_lin_a [128][64]
            int n = e >> 6, k = e & 63;
            wt_lin_a[e] = __float2bfloat16(ldf(lin_a_w, (size_t)k * 128 + n, isb));
        } else if (e < 12288) {    // wt_lin_b [128][32]
            int r = e - 8192; int n = r >> 5, k = r & 31;
            wt_lin_b[r] = __float2bfloat16(ldf(lin_b_w, (size_t)k * 128 + n, isb));
        } else if (e < 77824) {    // wt_alin [4][128][128]
            int r = e - 12288; int s = r >> 14, rem = r & 16383;
            int n = rem >> 7, k = rem & 127;
            wt_alin[r] = __float2bfloat16(ldf(a_lin_w, (size_t)s * 16384 + (size_t)k * 128 + n, isb));
        }
    } else {                       // kqv bias, lt = b-205; layout [k|v|q]; k scaled by LOG2E
        int lt = b - 205, j = t;
        float out;
        if (j < 128) {
            int h = j >> 5, e = j & 31;
            float s = ldf(p_rel, lt * Hh + h, isb) * INV_SQRT_D * LOG2E;
            float sum = 0.f;
            size_t kb0 = (size_t)lt * 128 + h * 32;
            size_t ar0 = ((size_t)lt * Hh + h) * 1024 + e;
            #pragma unroll
            for (int d = 0; d < 32; ++d) sum += ldf(k_b, kb0 + d, isb) * ldf(a_rel, ar0 + d * 32, isb);
            out = sum * s;
        } else if (j < 256) {
            int jj = j - 128; int h = jj >> 5, e = jj & 31;
            float sum = 0.f;
            size_t vb0 = (size_t)lt * 128 + h * 32;
            size_t mr0 = ((size_t)lt * Hh + h) * 1024 + e;
            #pragma unroll
            for (int d = 0; d < 32; ++d) sum += ldf(v_b, vb0 + d, isb) * ldf(m_rel, mr0 + d * 32, isb);
            out = sum;
        } else {
            out = ldf(q_b, (size_t)lt * 128 + (j - 256), isb);
        }
        b_kqv[(size_t)lt * 384 + j] = out;
    }
}

// ---------------- fused KQV weight prep: Wt[lt][384][128] bf16, layout [k|v|q] ----------------
__global__ void k_prep_kqv_w(const void* __restrict__ k_w, const void* __restrict__ q_w,
                             const void* __restrict__ v_w, const void* __restrict__ a_rel,
                             const void* __restrict__ m_rel, const void* __restrict__ p_rel,
                             bf16* __restrict__ Wt, const int* __restrict__ dflag) {
    int isb = dflag[0];
    int b = blockIdx.x;          // lt*128 + c (c = K index)
    int lt = b >> 7, c = b & 127;
    int j = threadIdx.x;         // 0..383 (N index)
    float out;
    if (j < 128) {               // k' scaled by p_rel/sqrt(D)*log2(e)
        int h = j >> 5, e = j & 31;
        float s = ldf(p_rel, lt * Hh + h, isb) * INV_SQRT_D * LOG2E;
        float sum = 0.f;
        size_t kw0 = ((size_t)lt * 128 + c) * 128 + h * 32;
        size_t ar0 = ((size_t)lt * Hh + h) * 1024 + e;
        #pragma unroll
        for (int d = 0; d < 32; ++d) sum += ldf(k_w, kw0 + d, isb) * ldf(a_rel, ar0 + d * 32, isb);
        out = sum * s;
    } else if (j < 256) {        // v'
        int jj = j - 128; int h = jj >> 5, e = jj & 31;
        float sum = 0.f;
        size_t vw0 = ((size_t)lt * 128 + c) * 128 + h * 32;
        size_t mr0 = ((size_t)lt * Hh + h) * 1024 + e;
        #pragma unroll
        for (int d = 0; d < 32; ++d) sum += ldf(v_w, vw0 + d, isb) * ldf(m_rel, mr0 + d * 32, isb);
        out = sum;
    } else {                     // q
        out = ldf(q_w, ((size_t)lt * 128 + c) * 128 + (j - 256), isb);
    }
    Wt[((size_t)lt * 384 + j) * 128 + c] = __float2bfloat16(out);
}

// ---------------- CSR build (both directions per launch) ----------------
__global__ void k_hist(const int* __restrict__ d0, const int* __restrict__ d1,
                       int* __restrict__ deg0, int* __restrict__ deg1) {
    int i = blockIdx.x * 256 + threadIdx.x;
    if (i >= NEe) return;
    if (blockIdx.y == 0) atomicAdd(&deg0[d0[i]], 1);
    else                 atomicAdd(&deg1[d1[i]], 1);
}

__global__ void k_scanA(const int* __restrict__ deg0, const int* __restrict__ deg1,
                        int* __restrict__ ex0, int* __restrict__ ex1,
                        int* __restrict__ bs0, int* __restrict__ bs1, int n) {
    const int* deg = blockIdx.y ? deg1 : deg0;
    int* excl = blockIdx.y ? ex1 : ex0;
    int* bsum = blockIdx.y ? bs1 : bs0;
    __shared__ int buf[256];
    int tid = threadIdx.x;
    int i = blockIdx.x * 256 + tid;
    int v = (i < n) ? deg[i] : 0;
    buf[tid] = v;
    __syncthreads();
    for (int off = 1; off < 256; off <<= 1) {
        int u = (tid >= off) ? buf[tid - off] : 0;
        __syncthreads();
        buf[tid] += u;
        __syncthreads();
    }
    int incl = buf[tid];
    if (i < n) excl[i] = incl - v;
    if (tid == 255) bsum[blockIdx.x] = incl;
}

__global__ void k_scanB(int* __restrict__ bs0, int* __restrict__ bs1, int nb) {
    int* bsum = blockIdx.x ? bs1 : bs0;
    __shared__ int buf[256];
    int tid = threadIdx.x;
    int v = (tid < nb) ? bsum[tid] : 0;
    buf[tid] = v;
    __syncthreads();
    for (int off = 1; off < 256; off <<= 1) {
        int u = (tid >= off) ? buf[tid - off] : 0;
        __syncthreads();
        buf[tid] += u;
        __syncthreads();
    }
    if (tid < nb) bsum[tid] = buf[tid] - v;
}

__global__ void k_scanC(int* __restrict__ rp0, int* __restrict__ rp1,
                        const int* __restrict__ bs0, const int* __restrict__ bs1,
                        int* __restrict__ cur0, int* __restrict__ cur1, int n) {
    int* rowptr = blockIdx.y ? rp1 : rp0;
    const int* bsum = blockIdx.y ? bs1 : bs0;
    int* cursor = blockIdx.y ? cur1 : cur0;
    int i = blockIdx.x * 256 + threadIdx.x;
    if (i < n) {
        int v = rowptr[i] + bsum[i >> 8];
        rowptr[i] = v;
        cursor[i] = v;
    }
    if (i == 0) rowptr[n] = NEe;
}

__global__ void k_scatter(const int* __restrict__ e0, const int* __restrict__ e1,
                          int* __restrict__ cur0, int* __restrict__ cur1,
                          int* __restrict__ cs0, int* __restrict__ cs1) {
    int i = blockIdx.x * 256 + threadIdx.x;
    if (i >= NEe) return;
    const int* e = blockIdx.y ? e1 : e0;
    int* cursor = blockIdx.y ? cur1 : cur0;
    int* csr = blockIdx.y ? cs1 : cs0;
    int d = e[NEe + i];
    int p = atomicAdd(&cursor[d], 1);
    csr[p] = e[i];
}

// ---------------- LDS-staged MFMA GEMM ----------------
// FINAL=1: EPI must be 2; writes adaptive-dtype d_out at z*NAn*Cc instead of out0/out1.
template <int KK, int EPI, int FINAL = 0>
__global__ __launch_bounds__(256) void k_mmL(const bf16* __restrict__ A0, const bf16* __restrict__ A1,
                                             int lda,
                                             const bf16* __restrict__ W0, const bf16* __restrict__ W1,
                                             const float* __restrict__ bias0, const float* __restrict__ bias1,
                                             bf16* __restrict__ out0, bf16* __restrict__ out1, int ldo,
                                             const bf16* __restrict__ old0, const bf16* __restrict__ old1,
                                             const void* __restrict__ skipp, int si0, int si1,
                                             void* __restrict__ dout,
                                             const int* __restrict__ dflag) {
    constexpr int NK = KK / 32;
    constexpr int GPR = KK / 8;
    constexpr int SG = GPR + 1;
    __shared__ u16 ldsA[64 * SG * 8];
    __shared__ u16 ldsB[128 * SG * 8];

    int z = blockIdx.z;
    const bf16* A = z ? A1 : A0;
    const bf16* Wt = z ? W1 : W0;
    const float* bias = z ? bias1 : bias0;
    bf16* out = z ? out1 : out0;
    const bf16* oldx = z ? old1 : old0;
    int skip_idx = z ? si1 : si0;

    int tid = threadIdx.x;
    int r0 = blockIdx.x * 64;
    int n0 = blockIdx.y * 128;

    #pragma unroll
    for (int i = 0; i < 64 * GPR / 256; ++i) {
        int idx = tid + i * 256;
        int row = idx / GPR, g = idx % GPR;
        uint4 v = *(const uint4*)(A + (size_t)(r0 + row) * lda + g * 8);
        *(uint4*)&ldsA[(row * SG + g) * 8] = v;
    }
    #pragma unroll
    for (int i = 0; i < 128 * GPR / 256; ++i) {
        int idx = tid + i * 256;
        int row = idx / GPR, g = idx % GPR;
        uint4 v = *(const uint4*)(Wt + (size_t)(n0 + row) * KK + g * 8);
        *(uint4*)&ldsB[(row * SG + g) * 8] = v;
    }
    __syncthreads();

    int w = tid >> 6, l = tid & 63;
    int wr0 = (w & 1) * 32;
    int wc0 = (w >> 1) * 64;
    int lr = l & 15, kb = l >> 4;

    s16x8 af[2][NK];
    #pragma unroll
    for (int mt = 0; mt < 2; ++mt)
        #pragma unroll
        for (int kf = 0; kf < NK; ++kf) {
            int row = wr0 + mt * 16 + lr;
            af[mt][kf] = *(const s16x8*)&ldsA[(row * SG + kf * 4 + kb) * 8];
        }
    s16x8 bfr[4][NK];
    #pragma unroll
    for (int nt = 0; nt < 4; ++nt)
        #pragma unroll
        for (int kf = 0; kf < NK; ++kf) {
            int row = wc0 + nt * 16 + lr;
            bfr[nt][kf] = *(const s16x8*)&ldsB[(row * SG + kf * 4 + kb) * 8];
        }

    f32x4 acc[2][4] = {};
    #pragma unroll
    for (int kf = 0; kf < NK; ++kf)
        #pragma unroll
        for (int mt = 0; mt < 2; ++mt)
            #pragma unroll
            for (int nt = 0; nt < 4; ++nt)
                acc[mt][nt] = __builtin_amdgcn_mfma_f32_16x16x32_bf16(
                    af[mt][kf], bfr[nt][kf], acc[mt][nt], 0, 0, 0);

    int isb = dflag[0];
    float sg = 0.f;
    if (EPI == 2) {
        float sv = ldf(skipp, skip_idx, isb);
        sg = 1.f / (1.f + expf(-sv));
    }
    #pragma unroll
    for (int mt = 0; mt < 2; ++mt)
        #pragma unroll
        for (int nt = 0; nt < 4; ++nt) {
            int col = n0 + wc0 + nt * 16 + lr;
            float bv = bias[col];
            #pragma unroll
            for (int r = 0; r < 4; ++r) {
                int row = r0 + wr0 + mt * 16 + kb * 4 + r;
                float o = acc[mt][nt][r] + bv;
                if (EPI == 1) o = fmaxf(o, 0.f);
                if (EPI == 2) o = sg * o + (1.f - sg) * bf2f(oldx[(size_t)row * 128 + col]);
                if (FINAL) {
                    size_t oi = (size_t)z * NAn * Cc + (size_t)row * 128 + col;
                    if (isb) ((bf16*)dout)[oi] = __float2bfloat16(o);
                    else     ((float*)dout)[oi] = o;
                } else {
                    out[(size_t)row * ldo + col] = __float2bfloat16(o);
                }
            }
        }
}

// ---------------- fused edge aggregation v5 (unchanged from R15) ----------------
__global__ __launch_bounds__(256) void k_edge(const bf16* __restrict__ kv0, bf16* __restrict__ qm0,
                                              const int* __restrict__ rp0, const int* __restrict__ cs0,
                                              const bf16* __restrict__ kv1, bf16* __restrict__ qm1,
                                              const int* __restrict__ rp1, const int* __restrict__ cs1,
                                              int nblk0) {
    int dir = (blockIdx.x >= nblk0);
    int blk = dir ? (blockIdx.x - nblk0) : blockIdx.x;
    const bf16* kv = dir ? kv1 : kv0;
    bf16* qm = dir ? qm1 : qm0;
    const int* rowptr = dir ? rp1 : rp0;
    const int* csr = dir ? cs1 : cs0;

    int tid = threadIdx.x;
    int n = blk * 8 + (tid >> 5);       // node index (8 per block, 2 per wave)
    int l5 = tid & 31;
    int eg = l5 >> 3, hp = l5 & 7;
    bf16* qrow = qm + (size_t)n * 384 + 256;

    uint4 qv0 = *(const uint4*)(qrow + hp * 16);
    uint4 qv1 = *(const uint4*)(qrow + hp * 16 + 8);
#if HAVE_DOT2
    bf16x2 qb0 = as_b2(qv0.x), qb1 = as_b2(qv0.y), qb2 = as_b2(qv0.z), qb3 = as_b2(qv0.w);
    bf16x2 qb4 = as_b2(qv1.x), qb5 = as_b2(qv1.y), qb6 = as_b2(qv1.z), qb7 = as_b2(qv1.w);
#else
    float qf0 = lo_bf(qv0.x), qf1 = hi_bf(qv0.x), qf2 = lo_bf(qv0.y), qf3 = hi_bf(qv0.y);
    float qf4 = lo_bf(qv0.z), qf5 = hi_bf(qv0.z), qf6 = lo_bf(qv0.w), qf7 = hi_bf(qv0.w);
    float qf8 = lo_bf(qv1.x), qf9 = hi_bf(qv1.x), qfa = lo_bf(qv1.y), qfb = hi_bf(qv1.y);
    float qfc = lo_bf(qv1.z), qfd = hi_bf(qv1.z), qfe = lo_bf(qv1.w), qff = hi_bf(qv1.w);
#endif

    float den = 0.f;
    f32x2 a0 = {0.f,0.f}, a1 = {0.f,0.f}, a2 = {0.f,0.f}, a3 = {0.f,0.f};
    f32x2 a4 = {0.f,0.f}, a5 = {0.f,0.f}, a6 = {0.f,0.f}, a7 = {0.f,0.f};
    int e0 = rowptr[n], e1 = rowptr[n + 1];
    int sidx_n = 0;
    {
        int ee = e0 + eg;
        if (ee < e1) sidx_n = csr[ee];
    }
    for (int e = e0; e < e1; e += 4) {
        int sidx = sidx_n;
        bool valid = (e + eg) < e1;
        int en = e + 4 + eg;
        if (en < e1) sidx_n = csr[en];     // prefetch next iteration's index
        const bf16* row = kv + (size_t)sidx * 384;
        uint4 kw0 = *(const uint4*)(row + hp * 16);
        uint4 kw1 = *(const uint4*)(row + hp * 16 + 8);
        uint4 vw0 = *(const uint4*)(row + 128 + hp * 16);
        uint4 vw1 = *(const uint4*)(row + 128 + hp * 16 + 8);
#if HAVE_DOT2
        float part = __builtin_amdgcn_fdot2_f32_bf16(as_b2(kw0.x), qb0, 0.f, false);
        part = __builtin_amdgcn_fdot2_f32_bf16(as_b2(kw0.y), qb1, part, false);
        part = __builtin_amdgcn_fdot2_f32_bf16(as_b2(kw0.z), qb2, part, false);
        part = __builtin_amdgcn_fdot2_f32_bf16(as_b2(kw0.w), qb3, part, false);
        part = __builtin_amdgcn_fdot2_f32_bf16(as_b2(kw1.x), qb4, part, false);
        part = __builtin_amdgcn_fdot2_f32_bf16(as_b2(kw1.y), qb5, part, false);
        part = __builtin_amdgcn_fdot2_f32_bf16(as_b2(kw1.z), qb6, part, false);
        part = __builtin_amdgcn_fdot2_f32_bf16(as_b2(kw1.w), qb7, part, false);
#else
        float part = qf0 * lo_bf(kw0.x) + qf1 * hi_bf(kw0.x)
                   + qf2 * lo_bf(kw0.y) + qf3 * hi_bf(kw0.y)
                   + qf4 * lo_bf(kw0.z) + qf5 * hi_bf(kw0.z)
                   + qf6 * lo_bf(kw0.w) + qf7 * hi_bf(kw0.w)
                   + qf8 * lo_bf(kw1.x) + qf9 * hi_bf(kw1.x)
                   + qfa * lo_bf(kw1.y) + qfb * hi_bf(kw1.y)
                   + qfc * lo_bf(kw1.z) + qfd * hi_bf(kw1.z)
                   + qfe * lo_bf(kw1.w) + qff * hi_bf(kw1.w);
#endif
        part += __shfl_xor(part, 1);       // head = hp>>1: 2 lanes per head
        float wgt = valid ? exp2f(part) : 0.f;
        den += wgt;
        f32x2 w2; w2[0] = wgt; w2[1] = wgt;
        f32x2 t;
        t[0] = lo_bf(vw0.x); t[1] = hi_bf(vw0.x); a0 += w2 * t;
        t[0] = lo_bf(vw0.y); t[1] = hi_bf(vw0.y); a1 += w2 * t;
        t[0] = lo_bf(vw0.z); t[1] = hi_bf(vw0.z); a2 += w2 * t;
        t[0] = lo_bf(vw0.w); t[1] = hi_bf(vw0.w); a3 += w2 * t;
        t[0] = lo_bf(vw1.x); t[1] = hi_bf(vw1.x); a4 += w2 * t;
        t[0] = lo_bf(vw1.y); t[1] = hi_bf(vw1.y); a5 += w2 * t;
        t[0] = lo_bf(vw1.z); t[1] = hi_bf(vw1.z); a6 += w2 * t;
        t[0] = lo_bf(vw1.w); t[1] = hi_bf(vw1.w); a7 += w2 * t;
    }
    den += __shfl_xor(den, 8);
    den += __shfl_xor(den, 16);
    // Round 1 (xor 16): egs {0,1} own pairs 0..3, egs {2,3} own pairs 4..7.
    bool keepLo = (eg < 2);
    f32x2 s0 = keepLo ? a4 : a0;
    f32x2 s1 = keepLo ? a5 : a1;
    f32x2 s2 = keepLo ? a6 : a2;
    f32x2 s3 = keepLo ? a7 : a3;
    f32x2 r0v, r1v, r2v, r3v;
    r0v[0] = __shfl_xor(s0[0], 16); r0v[1] = __shfl_xor(s0[1], 16);
    r1v[0] = __shfl_xor(s1[0], 16); r1v[1] = __shfl_xor(s1[1], 16);
    r2v[0] = __shfl_xor(s2[0], 16); r2v[1] = __shfl_xor(s2[1], 16);
    r3v[0] = __shfl_xor(s3[0], 16); r3v[1] = __shfl_xor(s3[1], 16);
    f32x2 b0 = (keepLo ? a0 : a4) + r0v;
    f32x2 b1 = (keepLo ? a1 : a5) + r1v;
    f32x2 b2 = (keepLo ? a2 : a6) + r2v;
    f32x2 b3 = (keepLo ? a3 : a7) + r3v;
    // Round 2 (xor 8): even egs own (b0,b1), odd own (b2,b3).
    bool keep2 = !(eg & 1);
    f32x2 t0 = keep2 ? b2 : b0;
    f32x2 t1 = keep2 ? b3 : b1;
    f32x2 u0, u1;
    u0[0] = __shfl_xor(t0[0], 8); u0[1] = __shfl_xor(t0[1], 8);
    u1[0] = __shfl_xor(t1[0], 8); u1[1] = __shfl_xor(t1[1], 8);
    f32x2 c0 = (keep2 ? b0 : b2) + u0;   // cols hp*16 + 4*eg + 0,1
    f32x2 c1 = (keep2 ? b1 : b3) + u1;   // cols hp*16 + 4*eg + 2,3
    float inv = 1.f / (den + 1e-16f);
    u32 p0 = (u32)f2bu(gelu_f(c0[0] * inv)) | ((u32)f2bu(gelu_f(c0[1] * inv)) << 16);
    u32 p1 = (u32)f2bu(gelu_f(c1[0] * inv)) | ((u32)f2bu(gelu_f(c1[1] * inv)) << 16);
    uint2 st; st.x = p0; st.y = p1;
    *(uint2*)(qrow + hp * 16 + 4 * eg) = st;
}

extern "C" void kernel_launch(void* const* d_in, const int* in_sizes, int n_in,
                              void* d_out, int out_size, void* d_ws, size_t ws_size,
                              hipStream_t stream) {
    const void* x_a     = d_in[0];
    const void* x_b     = d_in[1];
    const int*  edge_ab = (const int*)d_in[2];
    const int*  edge_ba = (const int*)d_in[3];
    const void* lin_a_w = d_in[4];
    const void* lin_a_b = d_in[5];
    const void* lin_b_w = d_in[6];
    const void* lin_b_b = d_in[7];
    const void* k_w     = d_in[8];
    const void* k_b     = d_in[9];
    const void* q_w     = d_in[10];
    const void* q_b     = d_in[11];
    const void* v_w     = d_in[12];
    const void* v_b     = d_in[13];
    const void* a_rel   = d_in[14];
    const void* m_rel   = d_in[15];
    const void* p_rel   = d_in[16];
    const void* a_lin_w = d_in[17];
    const void* a_lin_b = d_in[18];
    const void* skip    = d_in[19];

    // -------- workspace layout --------
    char* p = (char*)d_ws;
    auto falloc = [&](size_t n) { float* r = (float*)p; p += n * sizeof(float); return r; };
    float* bias_lin = falloc(768);       // [lin_a_b | lin_b_b | a_lin_b(512)]
    float* b_kqv    = falloc(4 * 384);
    auto halloc = [&](size_t n) { bf16* r = (bf16*)p; p += n * sizeof(bf16); return r; };
    bf16* x_a_bf   = halloc((size_t)NAn * 64);
    bf16* x_b_bf   = halloc((size_t)NBn * 32);
    bf16* xa_bf    = halloc((size_t)NAn * Cc);
    bf16* xb_bf    = halloc((size_t)NBn * Cc);
    bf16* kqv_a    = halloc((size_t)NAn * 384);
    bf16* kqv_b    = halloc((size_t)NBn * 384);
    bf16* wt_lin_a = halloc(128 * 64);
    bf16* wt_lin_b = halloc(128 * 32);
    bf16* wt_kqv   = halloc(4 * 384 * 128);
    bf16* wt_alin  = halloc(4 * 128 * 128);
    auto ialloc = [&](size_t n) { int* r = (int*)p; p += n * sizeof(int); return r; };
    int* dflag     = ialloc(4);
    int* rowptr_ab = ialloc(NBn + 1);
    int* rowptr_ba = ialloc(NAn + 1);
    int* deg_ab    = ialloc(NBn);       // deg_ab/deg_ba adjacent -> zeroed by k_prep_small
    int* deg_ba    = ialloc(NAn);
    int* cursor_ab = ialloc(NBn);
    int* cursor_ba = ialloc(NAn);
    int* bsum_ab   = ialloc(256);
    int* bsum_ba   = ialloc(256);
    int* csr_ab    = ialloc(NEe);
    int* csr_ba    = ialloc(NEe);

    // -------- dtype detection --------
    k_detect<<<1, 256, 0, stream>>>((const u16*)x_a, 8192, dflag);

    // -------- weight prep (2 launches; prep_small also zeros deg) --------
    k_prep_small<<<209, 384, 0, stream>>>(lin_a_w, lin_a_b, lin_b_w, lin_b_b, a_lin_w, a_lin_b,
                                          k_b, q_b, v_b, a_rel, m_rel, p_rel,
                                          bias_lin, wt_lin_a, wt_lin_b, wt_alin, b_kqv,
                                          deg_ab, dflag);
    k_prep_kqv_w<<<512, 384, 0, stream>>>(k_w, q_w, v_w, a_rel, m_rel, p_rel, wt_kqv, dflag);

    // -------- x inputs -> bf16 (vectorized) --------
    k_convb<<<((NAn * 64 + NBn * 32) / 8 + 255) / 256, 256, 0, stream>>>(x_a, x_b, x_a_bf, x_b_bf, dflag);

    // -------- CSR build, both directions --------
    dim3 eg((NEe + 255) / 256, 2);
    k_hist<<<eg, 256, 0, stream>>>(edge_ab + NEe, edge_ba + NEe, deg_ab, deg_ba);
    int nblk = (NBn + 255) / 256; // 157
    k_scanA<<<dim3(nblk, 2), 256, 0, stream>>>(deg_ab, deg_ba, rowptr_ab, rowptr_ba,
                                               bsum_ab, bsum_ba, NBn);
    k_scanB<<<2, 256, 0, stream>>>(bsum_ab, bsum_ba, nblk);
    k_scanC<<<dim3(nblk, 2), 256, 0, stream>>>(rowptr_ab, rowptr_ba, bsum_ab, bsum_ba,
                                               cursor_ab, cursor_ba, NBn);
    k_scatter<<<eg, 256, 0, stream>>>(edge_ab, edge_ba, cursor_ab, cursor_ba, csr_ab, csr_ba);

    // -------- input linears + relu (LDS-staged) --------
    k_mmL<64, 1><<<dim3(NAn / 64, 1, 1), 256, 0, stream>>>(
        x_a_bf, x_a_bf, 64, wt_lin_a, wt_lin_a, bias_lin, bias_lin,
        xa_bf, xa_bf, 128, nullptr, nullptr, nullptr, 0, 0, nullptr, dflag);
    k_mmL<32, 1><<<dim3(NBn / 64, 1, 1), 256, 0, stream>>>(
        x_b_bf, x_b_bf, 32, wt_lin_b, wt_lin_b, bias_lin + 128, bias_lin + 128,
        xb_bf, xb_bf, 128, nullptr, nullptr, nullptr, 0, 0, nullptr, dflag);

    // -------- layers --------
    for (int l = 0; l < Ll; ++l) {
        int lt0 = l * 2 + 0, lt1 = l * 2 + 1;
        // kqv: LDS-staged, grid (625, 3, 2)
        k_mmL<128, 0><<<dim3(NAn / 64, 3, 2), 256, 0, stream>>>(
            xa_bf, xb_bf, 128,
            wt_kqv + (size_t)lt0 * 384 * 128, wt_kqv + (size_t)lt1 * 384 * 128,
            b_kqv + (size_t)lt0 * 384, b_kqv + (size_t)lt1 * 384,
            kqv_a, kqv_b, 384, nullptr, nullptr, nullptr, 0, 0, nullptr, dflag);
        int nblk0 = NBn / 8; // 5000 blocks per direction, 8 nodes/block
        k_edge<<<nblk0 + NAn / 8, 256, 0, stream>>>(
            kqv_a, kqv_b, rowptr_ab, csr_ab,
            kqv_b, kqv_a, rowptr_ba, csr_ba, nblk0);
        // a_lin + skip blend; final layer writes d_out directly (adaptive dtype)
        if (l == Ll - 1) {
            k_mmL<128, 2, 1><<<dim3(NAn / 64, 1, 2), 256, 0, stream>>>(
                kqv_a + 256, kqv_b + 256, 384,
                wt_alin + (size_t)lt0 * 128 * 128, wt_alin + (size_t)lt1 * 128 * 128,
                bias_lin + 256 + (size_t)lt0 * 128, bias_lin + 256 + (size_t)lt1 * 128,
                nullptr, nullptr, 128, xa_bf, xb_bf, skip, lt0, lt1, d_out, dflag);
        } else {
            k_mmL<128, 2><<<dim3(NAn / 64, 1, 2), 256, 0, stream>>>(
                kqv_a + 256, kqv_b + 256, 384,
                wt_alin + (size_t)lt0 * 128 * 128, wt_alin + (size_t)lt1 * 128 * 128,
                bias_lin + 256 + (size_t)lt0 * 128, bias_lin + 256 + (size_t)lt1 * 128,
                xa_bf, xb_bf, 128, xa_bf, xb_bf, skip, lt0, lt1, nullptr, dflag);
        }
    }
}

// Round 17
// 240.656 us; speedup vs baseline: 1.0458x; 1.0269x over previous
//
#include <hip/hip_runtime.h>
#include <hip/hip_bf16.h>
#include <math.h>

#define NAn 40000
#define NBn 40000
#define NEe 250000
#define Cc 128
#define Hh 4
#define Ll 2
static constexpr float INV_SQRT_D = 0.17677669529663687f; // 1/sqrt(32)
static constexpr float LOG2E = 1.4426950408889634f;

typedef __hip_bfloat16 bf16;
typedef unsigned short u16;
typedef unsigned int u32;
typedef short s16x8 __attribute__((ext_vector_type(8)));
typedef float f32x4 __attribute__((ext_vector_type(4)));
typedef float f32x2 __attribute__((ext_vector_type(2)));
typedef __bf16 bf16x2 __attribute__((ext_vector_type(2)));

#if defined(__has_builtin)
#  if __has_builtin(__builtin_amdgcn_fdot2_f32_bf16)
#    define HAVE_DOT2 1
#  endif
#endif
#ifndef HAVE_DOT2
#  define HAVE_DOT2 0
#endif

__device__ __forceinline__ float bf2f(bf16 x) { return __bfloat162float(x); }
__device__ __forceinline__ float lo_bf(u32 w) { return __uint_as_float(w << 16); }
__device__ __forceinline__ float hi_bf(u32 w) { return __uint_as_float(w & 0xffff0000u); }
__device__ __forceinline__ float ldf(const void* p, size_t i, int isb) {
    return isb ? bf2f(((const bf16*)p)[i]) : ((const float*)p)[i];
}
__device__ __forceinline__ u16 f2bu(float v) {
    union { bf16 b; u16 u; } c; c.b = __float2bfloat16(v); return c.u;
}
__device__ __forceinline__ float gelu_f(float v) {
    return 0.5f * v * (1.f + erff(v * 0.70710678118f));
}
__device__ __forceinline__ bf16x2 as_b2(u32 w) {
    union { u32 u; bf16x2 v; } c; c.u = w; return c.v;
}

// ---------------- dtype detection ----------------
__global__ void k_detect(const u16* __restrict__ x, int n, int* __restrict__ flag) {
    __shared__ float smax[256];
    int tid = threadIdx.x;
    float m = 0.f;
    for (int i = tid; i < n; i += 256) {
        float v = fabsf(__uint_as_float(((u32)x[i]) << 16));
        if (v != v) v = 1e30f;
        m = fmaxf(m, v);
    }
    smax[tid] = m;
    __syncthreads();
    for (int s = 128; s > 0; s >>= 1) {
        if (tid < s) smax[tid] = fmaxf(smax[tid], smax[tid + s]);
        __syncthreads();
    }
    if (tid == 0) flag[0] = (smax[0] > 1e4f) ? 0 : 1;
}

// ---------------- merged setup: prep_small (b<209) | prep_kqv_w (b<721) | convb ----------------
__global__ void k_setup(const void* __restrict__ lin_a_w, const void* __restrict__ lin_a_b,
                        const void* __restrict__ lin_b_w, const void* __restrict__ lin_b_b,
                        const void* __restrict__ a_lin_w, const void* __restrict__ a_lin_b,
                        const void* __restrict__ k_w, const void* __restrict__ k_b,
                        const void* __restrict__ q_w, const void* __restrict__ q_b,
                        const void* __restrict__ v_w, const void* __restrict__ v_b,
                        const void* __restrict__ a_rel, const void* __restrict__ m_rel,
                        const void* __restrict__ p_rel,
                        const void* __restrict__ x_a, const void* __restrict__ x_b,
                        float* __restrict__ bias_lin, bf16* __restrict__ wt_lin_a,
                        bf16* __restrict__ wt_lin_b, bf16* __restrict__ wt_alin,
                        bf16* __restrict__ wt_kqv, float* __restrict__ b_kqv,
                        bf16* __restrict__ x_a_bf, bf16* __restrict__ x_b_bf,
                        int* __restrict__ deg, const int* __restrict__ dflag) {
    int isb = dflag[0];
    int b = blockIdx.x, t = threadIdx.x;
    if (b < 209) {
        // ---- prep_small + deg zeroing ----
        int z = b * 384 + t;
        if (z < 2 * NAn) deg[z] = 0;
        if (b < 2) {
            int i = b * 384 + t;
            if (i < 768) {
                float v = (i < 128) ? ldf(lin_a_b, i, isb)
                        : (i < 256) ? ldf(lin_b_b, i - 128, isb)
                                    : ldf(a_lin_b, i - 256, isb);
                bias_lin[i] = v;
            }
        } else if (b < 205) {
            int e = (b - 2) * 384 + t;
            if (e < 8192) {            // wt_lin_a [128][64]
                int n = e >> 6, k = e & 63;
                wt_lin_a[e] = __float2bfloat16(ldf(lin_a_w, (size_t)k * 128 + n, isb));
            } else if (e < 12288) {    // wt_lin_b [128][32]
                int r = e - 8192; int n = r >> 5, k = r & 31;
                wt_lin_b[r] = __float2bfloat16(ldf(lin_b_w, (size_t)k * 128 + n, isb));
            } else if (e < 77824) {    // wt_alin [4][128][128]
                int r = e - 12288; int s = r >> 14, rem = r & 16383;
                int n = rem >> 7, k = rem & 127;
                wt_alin[r] = __float2bfloat16(ldf(a_lin_w, (size_t)s * 16384 + (size_t)k * 128 + n, isb));
            }
        } else {                       // kqv bias, lt = b-205; layout [k|v|q]; k scaled by LOG2E
            int lt = b - 205, j = t;
            float out;
            if (j < 128) {
                int h = j >> 5, e = j & 31;
                float s = ldf(p_rel, lt * Hh + h, isb) * INV_SQRT_D * LOG2E;
                float sum = 0.f;
                size_t kb0 = (size_t)lt * 128 + h * 32;
                size_t ar0 = ((size_t)lt * Hh + h) * 1024 + e;
                #pragma unroll
                for (int d = 0; d < 32; ++d) sum += ldf(k_b, kb0 + d, isb) * ldf(a_rel, ar0 + d * 32, isb);
                out = sum * s;
            } else if (j < 256) {
                int jj = j - 128; int h = jj >> 5, e = jj & 31;
                float sum = 0.f;
                size_t vb0 = (size_t)lt * 128 + h * 32;
                size_t mr0 = ((size_t)lt * Hh + h) * 1024 + e;
                #pragma unroll
                for (int d = 0; d < 32; ++d) sum += ldf(v_b, vb0 + d, isb) * ldf(m_rel, mr0 + d * 32, isb);
                out = sum;
            } else {
                out = ldf(q_b, (size_t)lt * 128 + (j - 256), isb);
            }
            b_kqv[(size_t)lt * 384 + j] = out;
        }
    } else if (b < 721) {
        // ---- prep_kqv_w: Wt[lt][384][128] bf16, layout [k|v|q] ----
        int bb = b - 209;            // lt*128 + c
        int lt = bb >> 7, c = bb & 127;
        int j = t;                   // 0..383 (N index)
        float out;
        if (j < 128) {               // k' scaled by p_rel/sqrt(D)*log2(e)
            int h = j >> 5, e = j & 31;
            float s = ldf(p_rel, lt * Hh + h, isb) * INV_SQRT_D * LOG2E;
            float sum = 0.f;
            size_t kw0 = ((size_t)lt * 128 + c) * 128 + h * 32;
            size_t ar0 = ((size_t)lt * Hh + h) * 1024 + e;
            #pragma unroll
            for (int d = 0; d < 32; ++d) sum += ldf(k_w, kw0 + d, isb) * ldf(a_rel, ar0 + d * 32, isb);
            out = sum * s;
        } else if (j < 256) {        // v'
            int jj = j - 128; int h = jj >> 5, e = jj & 31;
            float sum = 0.f;
            size_t vw0 = ((size_t)lt * 128 + c) * 128 + h * 32;
            size_t mr0 = ((size_t)lt * Hh + h) * 1024 + e;
            #pragma unroll
            for (int d = 0; d < 32; ++d) sum += ldf(v_w, vw0 + d, isb) * ldf(m_rel, mr0 + d * 32, isb);
            out = sum;
        } else {                     // q
            out = ldf(q_w, ((size_t)lt * 128 + c) * 128 + (j - 256), isb);
        }
        wt_kqv[((size_t)lt * 384 + j) * 128 + c] = __float2bfloat16(out);
    } else {
        // ---- convb: 8-elem vector groups ----
        int g = (b - 721) * 384 + t;
        int na8 = NAn * 64 / 8;                    // 320000
        if (g >= na8 + NBn * 32 / 8) return;       // 480000 total
        const void* src; bf16* dst; int j;
        if (g < na8) { src = x_a; dst = x_a_bf; j = g; }
        else         { src = x_b; dst = x_b_bf; j = g - na8; }
        if (isb) {
            *(uint4*)(dst + (size_t)j * 8) = ((const uint4*)src)[j];
        } else {
            const float* s = (const float*)src;
            union { u16 o[8]; uint4 v; } pk;
            #pragma unroll
            for (int i = 0; i < 8; ++i) pk.o[i] = f2bu(s[(size_t)j * 8 + i]);
            *(uint4*)(dst + (size_t)j * 8) = pk.v;
        }
    }
}

// ---------------- CSR build (both directions per launch) ----------------
__global__ void k_hist(const int* __restrict__ d0, const int* __restrict__ d1,
                       int* __restrict__ deg0, int* __restrict__ deg1) {
    int i = blockIdx.x * 256 + threadIdx.x;
    if (i >= NEe) return;
    if (blockIdx.y == 0) atomicAdd(&deg0[d0[i]], 1);
    else                 atomicAdd(&deg1[d1[i]], 1);
}

__global__ void k_scanA(const int* __restrict__ deg0, const int* __restrict__ deg1,
                        int* __restrict__ ex0, int* __restrict__ ex1,
                        int* __restrict__ bs0, int* __restrict__ bs1, int n) {
    const int* deg = blockIdx.y ? deg1 : deg0;
    int* excl = blockIdx.y ? ex1 : ex0;
    int* bsum = blockIdx.y ? bs1 : bs0;
    __shared__ int buf[256];
    int tid = threadIdx.x;
    int i = blockIdx.x * 256 + tid;
    int v = (i < n) ? deg[i] : 0;
    buf[tid] = v;
    __syncthreads();
    for (int off = 1; off < 256; off <<= 1) {
        int u = (tid >= off) ? buf[tid - off] : 0;
        __syncthreads();
        buf[tid] += u;
        __syncthreads();
    }
    int incl = buf[tid];
    if (i < n) excl[i] = incl - v;
    if (tid == 255) bsum[blockIdx.x] = incl;
}

__global__ void k_scanB(int* __restrict__ bs0, int* __restrict__ bs1, int nb) {
    int* bsum = blockIdx.x ? bs1 : bs0;
    __shared__ int buf[256];
    int tid = threadIdx.x;
    int v = (tid < nb) ? bsum[tid] : 0;
    buf[tid] = v;
    __syncthreads();
    for (int off = 1; off < 256; off <<= 1) {
        int u = (tid >= off) ? buf[tid - off] : 0;
        __syncthreads();
        buf[tid] += u;
        __syncthreads();
    }
    if (tid < nb) bsum[tid] = buf[tid] - v;
}

__global__ void k_scanC(int* __restrict__ rp0, int* __restrict__ rp1,
                        const int* __restrict__ bs0, const int* __restrict__ bs1,
                        int* __restrict__ cur0, int* __restrict__ cur1, int n) {
    int* rowptr = blockIdx.y ? rp1 : rp0;
    const int* bsum = blockIdx.y ? bs1 : bs0;
    int* cursor = blockIdx.y ? cur1 : cur0;
    int i = blockIdx.x * 256 + threadIdx.x;
    if (i < n) {
        int v = rowptr[i] + bsum[i >> 8];
        rowptr[i] = v;
        cursor[i] = v;
    }
    if (i == 0) rowptr[n] = NEe;
}

__global__ void k_scatter(const int* __restrict__ e0, const int* __restrict__ e1,
                          int* __restrict__ cur0, int* __restrict__ cur1,
                          int* __restrict__ cs0, int* __restrict__ cs1) {
    int i = blockIdx.x * 256 + threadIdx.x;
    if (i >= NEe) return;
    const int* e = blockIdx.y ? e1 : e0;
    int* cursor = blockIdx.y ? cur1 : cur0;
    int* csr = blockIdx.y ? cs1 : cs0;
    int d = e[NEe + i];
    int p = atomicAdd(&cursor[d], 1);
    csr[p] = e[i];
}

// ---------------- LDS-staged MFMA GEMM (unchanged from R16) ----------------
// FINAL=1: EPI must be 2; writes adaptive-dtype d_out at z*NAn*Cc instead of out0/out1.
template <int KK, int EPI, int FINAL = 0>
__global__ __launch_bounds__(256) void k_mmL(const bf16* __restrict__ A0, const bf16* __restrict__ A1,
                                             int lda,
                                             const bf16* __restrict__ W0, const bf16* __restrict__ W1,
                                             const float* __restrict__ bias0, const float* __restrict__ bias1,
                                             bf16* __restrict__ out0, bf16* __restrict__ out1, int ldo,
                                             const bf16* __restrict__ old0, const bf16* __restrict__ old1,
                                             const void* __restrict__ skipp, int si0, int si1,
                                             void* __restrict__ dout,
                                             const int* __restrict__ dflag) {
    constexpr int NK = KK / 32;
    constexpr int GPR = KK / 8;
    constexpr int SG = GPR + 1;
    __shared__ u16 ldsA[64 * SG * 8];
    __shared__ u16 ldsB[128 * SG * 8];

    int z = blockIdx.z;
    const bf16* A = z ? A1 : A0;
    const bf16* Wt = z ? W1 : W0;
    const float* bias = z ? bias1 : bias0;
    bf16* out = z ? out1 : out0;
    const bf16* oldx = z ? old1 : old0;
    int skip_idx = z ? si1 : si0;

    int tid = threadIdx.x;
    int r0 = blockIdx.x * 64;
    int n0 = blockIdx.y * 128;

    #pragma unroll
    for (int i = 0; i < 64 * GPR / 256; ++i) {
        int idx = tid + i * 256;
        int row = idx / GPR, g = idx % GPR;
        uint4 v = *(const uint4*)(A + (size_t)(r0 + row) * lda + g * 8);
        *(uint4*)&ldsA[(row * SG + g) * 8] = v;
    }
    #pragma unroll
    for (int i = 0; i < 128 * GPR / 256; ++i) {
        int idx = tid + i * 256;
        int row = idx / GPR, g = idx % GPR;
        uint4 v = *(const uint4*)(Wt + (size_t)(n0 + row) * KK + g * 8);
        *(uint4*)&ldsB[(row * SG + g) * 8] = v;
    }
    __syncthreads();

    int w = tid >> 6, l = tid & 63;
    int wr0 = (w & 1) * 32;
    int wc0 = (w >> 1) * 64;
    int lr = l & 15, kb = l >> 4;

    s16x8 af[2][NK];
    #pragma unroll
    for (int mt = 0; mt < 2; ++mt)
        #pragma unroll
        for (int kf = 0; kf < NK; ++kf) {
            int row = wr0 + mt * 16 + lr;
            af[mt][kf] = *(const s16x8*)&ldsA[(row * SG + kf * 4 + kb) * 8];
        }
    s16x8 bfr[4][NK];
    #pragma unroll
    for (int nt = 0; nt < 4; ++nt)
        #pragma unroll
        for (int kf = 0; kf < NK; ++kf) {
            int row = wc0 + nt * 16 + lr;
            bfr[nt][kf] = *(const s16x8*)&ldsB[(row * SG + kf * 4 + kb) * 8];
        }

    f32x4 acc[2][4] = {};
    #pragma unroll
    for (int kf = 0; kf < NK; ++kf)
        #pragma unroll
        for (int mt = 0; mt < 2; ++mt)
            #pragma unroll
            for (int nt = 0; nt < 4; ++nt)
                acc[mt][nt] = __builtin_amdgcn_mfma_f32_16x16x32_bf16(
                    af[mt][kf], bfr[nt][kf], acc[mt][nt], 0, 0, 0);

    int isb = dflag[0];
    float sg = 0.f;
    if (EPI == 2) {
        float sv = ldf(skipp, skip_idx, isb);
        sg = 1.f / (1.f + expf(-sv));
    }
    #pragma unroll
    for (int mt = 0; mt < 2; ++mt)
        #pragma unroll
        for (int nt = 0; nt < 4; ++nt) {
            int col = n0 + wc0 + nt * 16 + lr;
            float bv = bias[col];
            #pragma unroll
            for (int r = 0; r < 4; ++r) {
                int row = r0 + wr0 + mt * 16 + kb * 4 + r;
                float o = acc[mt][nt][r] + bv;
                if (EPI == 1) o = fmaxf(o, 0.f);
                if (EPI == 2) o = sg * o + (1.f - sg) * bf2f(oldx[(size_t)row * 128 + col]);
                if (FINAL) {
                    size_t oi = (size_t)z * NAn * Cc + (size_t)row * 128 + col;
                    if (isb) ((bf16*)dout)[oi] = __float2bfloat16(o);
                    else     ((float*)dout)[oi] = o;
                } else {
                    out[(size_t)row * ldo + col] = __float2bfloat16(o);
                }
            }
        }
}

// ---------------- fused edge aggregation v5 (unchanged from R15/R16) ----------------
__global__ __launch_bounds__(256) void k_edge(const bf16* __restrict__ kv0, bf16* __restrict__ qm0,
                                              const int* __restrict__ rp0, const int* __restrict__ cs0,
                                              const bf16* __restrict__ kv1, bf16* __restrict__ qm1,
                                              const int* __restrict__ rp1, const int* __restrict__ cs1,
                                              int nblk0) {
    int dir = (blockIdx.x >= nblk0);
    int blk = dir ? (blockIdx.x - nblk0) : blockIdx.x;
    const bf16* kv = dir ? kv1 : kv0;
    bf16* qm = dir ? qm1 : qm0;
    const int* rowptr = dir ? rp1 : rp0;
    const int* csr = dir ? cs1 : cs0;

    int tid = threadIdx.x;
    int n = blk * 8 + (tid >> 5);       // node index (8 per block, 2 per wave)
    int l5 = tid & 31;
    int eg = l5 >> 3, hp = l5 & 7;
    bf16* qrow = qm + (size_t)n * 384 + 256;

    uint4 qv0 = *(const uint4*)(qrow + hp * 16);
    uint4 qv1 = *(const uint4*)(qrow + hp * 16 + 8);
#if HAVE_DOT2
    bf16x2 qb0 = as_b2(qv0.x), qb1 = as_b2(qv0.y), qb2 = as_b2(qv0.z), qb3 = as_b2(qv0.w);
    bf16x2 qb4 = as_b2(qv1.x), qb5 = as_b2(qv1.y), qb6 = as_b2(qv1.z), qb7 = as_b2(qv1.w);
#else
    float qf0 = lo_bf(qv0.x), qf1 = hi_bf(qv0.x), qf2 = lo_bf(qv0.y), qf3 = hi_bf(qv0.y);
    float qf4 = lo_bf(qv0.z), qf5 = hi_bf(qv0.z), qf6 = lo_bf(qv0.w), qf7 = hi_bf(qv0.w);
    float qf8 = lo_bf(qv1.x), qf9 = hi_bf(qv1.x), qfa = lo_bf(qv1.y), qfb = hi_bf(qv1.y);
    float qfc = lo_bf(qv1.z), qfd = hi_bf(qv1.z), qfe = lo_bf(qv1.w), qff = hi_bf(qv1.w);
#endif

    float den = 0.f;
    f32x2 a0 = {0.f,0.f}, a1 = {0.f,0.f}, a2 = {0.f,0.f}, a3 = {0.f,0.f};
    f32x2 a4 = {0.f,0.f}, a5 = {0.f,0.f}, a6 = {0.f,0.f}, a7 = {0.f,0.f};
    int e0 = rowptr[n], e1 = rowptr[n + 1];
    int sidx_n = 0;
    {
        int ee = e0 + eg;
        if (ee < e1) sidx_n = csr[ee];
    }
    for (int e = e0; e < e1; e += 4) {
        int sidx = sidx_n;
        bool valid = (e + eg) < e1;
        int en = e + 4 + eg;
        if (en < e1) sidx_n = csr[en];     // prefetch next iteration's index
        const bf16* row = kv + (size_t)sidx * 384;
        uint4 kw0 = *(const uint4*)(row + hp * 16);
        uint4 kw1 = *(const uint4*)(row + hp * 16 + 8);
        uint4 vw0 = *(const uint4*)(row + 128 + hp * 16);
        uint4 vw1 = *(const uint4*)(row + 128 + hp * 16 + 8);
#if HAVE_DOT2
        float part = __builtin_amdgcn_fdot2_f32_bf16(as_b2(kw0.x), qb0, 0.f, false);
        part = __builtin_amdgcn_fdot2_f32_bf16(as_b2(kw0.y), qb1, part, false);
        part = __builtin_amdgcn_fdot2_f32_bf16(as_b2(kw0.z), qb2, part, false);
        part = __builtin_amdgcn_fdot2_f32_bf16(as_b2(kw0.w), qb3, part, false);
        part = __builtin_amdgcn_fdot2_f32_bf16(as_b2(kw1.x), qb4, part, false);
        part = __builtin_amdgcn_fdot2_f32_bf16(as_b2(kw1.y), qb5, part, false);
        part = __builtin_amdgcn_fdot2_f32_bf16(as_b2(kw1.z), qb6, part, false);
        part = __builtin_amdgcn_fdot2_f32_bf16(as_b2(kw1.w), qb7, part, false);
#else
        float part = qf0 * lo_bf(kw0.x) + qf1 * hi_bf(kw0.x)
                   + qf2 * lo_bf(kw0.y) + qf3 * hi_bf(kw0.y)
                   + qf4 * lo_bf(kw0.z) + qf5 * hi_bf(kw0.z)
                   + qf6 * lo_bf(kw0.w) + qf7 * hi_bf(kw0.w)
                   + qf8 * lo_bf(kw1.x) + qf9 * hi_bf(kw1.x)
                   + qfa * lo_bf(kw1.y) + qfb * hi_bf(kw1.y)
                   + qfc * lo_bf(kw1.z) + qfd * hi_bf(kw1.z)
                   + qfe * lo_bf(kw1.w) + qff * hi_bf(kw1.w);
#endif
        part += __shfl_xor(part, 1);       // head = hp>>1: 2 lanes per head
        float wgt = valid ? exp2f(part) : 0.f;
        den += wgt;
        f32x2 w2; w2[0] = wgt; w2[1] = wgt;
        f32x2 t;
        t[0] = lo_bf(vw0.x); t[1] = hi_bf(vw0.x); a0 += w2 * t;
        t[0] = lo_bf(vw0.y); t[1] = hi_bf(vw0.y); a1 += w2 * t;
        t[0] = lo_bf(vw0.z); t[1] = hi_bf(vw0.z); a2 += w2 * t;
        t[0] = lo_bf(vw0.w); t[1] = hi_bf(vw0.w); a3 += w2 * t;
        t[0] = lo_bf(vw1.x); t[1] = hi_bf(vw1.x); a4 += w2 * t;
        t[0] = lo_bf(vw1.y); t[1] = hi_bf(vw1.y); a5 += w2 * t;
        t[0] = lo_bf(vw1.z); t[1] = hi_bf(vw1.z); a6 += w2 * t;
        t[0] = lo_bf(vw1.w); t[1] = hi_bf(vw1.w); a7 += w2 * t;
    }
    den += __shfl_xor(den, 8);
    den += __shfl_xor(den, 16);
    // Round 1 (xor 16): egs {0,1} own pairs 0..3, egs {2,3} own pairs 4..7.
    bool keepLo = (eg < 2);
    f32x2 s0 = keepLo ? a4 : a0;
    f32x2 s1 = keepLo ? a5 : a1;
    f32x2 s2 = keepLo ? a6 : a2;
    f32x2 s3 = keepLo ? a7 : a3;
    f32x2 r0v, r1v, r2v, r3v;
    r0v[0] = __shfl_xor(s0[0], 16); r0v[1] = __shfl_xor(s0[1], 16);
    r1v[0] = __shfl_xor(s1[0], 16); r1v[1] = __shfl_xor(s1[1], 16);
    r2v[0] = __shfl_xor(s2[0], 16); r2v[1] = __shfl_xor(s2[1], 16);
    r3v[0] = __shfl_xor(s3[0], 16); r3v[1] = __shfl_xor(s3[1], 16);
    f32x2 b0 = (keepLo ? a0 : a4) + r0v;
    f32x2 b1 = (keepLo ? a1 : a5) + r1v;
    f32x2 b2 = (keepLo ? a2 : a6) + r2v;
    f32x2 b3 = (keepLo ? a3 : a7) + r3v;
    // Round 2 (xor 8): even egs own (b0,b1), odd own (b2,b3).
    bool keep2 = !(eg & 1);
    f32x2 t0 = keep2 ? b2 : b0;
    f32x2 t1 = keep2 ? b3 : b1;
    f32x2 u0, u1;
    u0[0] = __shfl_xor(t0[0], 8); u0[1] = __shfl_xor(t0[1], 8);
    u1[0] = __shfl_xor(t1[0], 8); u1[1] = __shfl_xor(t1[1], 8);
    f32x2 c0 = (keep2 ? b0 : b2) + u0;   // cols hp*16 + 4*eg + 0,1
    f32x2 c1 = (keep2 ? b1 : b3) + u1;   // cols hp*16 + 4*eg + 2,3
    float inv = 1.f / (den + 1e-16f);
    u32 p0 = (u32)f2bu(gelu_f(c0[0] * inv)) | ((u32)f2bu(gelu_f(c0[1] * inv)) << 16);
    u32 p1 = (u32)f2bu(gelu_f(c1[0] * inv)) | ((u32)f2bu(gelu_f(c1[1] * inv)) << 16);
    uint2 st; st.x = p0; st.y = p1;
    *(uint2*)(qrow + hp * 16 + 4 * eg) = st;
}

extern "C" void kernel_launch(void* const* d_in, const int* in_sizes, int n_in,
                              void* d_out, int out_size, void* d_ws, size_t ws_size,
                              hipStream_t stream) {
    const void* x_a     = d_in[0];
    const void* x_b     = d_in[1];
    const int*  edge_ab = (const int*)d_in[2];
    const int*  edge_ba = (const int*)d_in[3];
    const void* lin_a_w = d_in[4];
    const void* lin_a_b = d_in[5];
    const void* lin_b_w = d_in[6];
    const void* lin_b_b = d_in[7];
    const void* k_w     = d_in[8];
    const void* k_b     = d_in[9];
    const void* q_w     = d_in[10];
    const void* q_b     = d_in[11];
    const void* v_w     = d_in[12];
    const void* v_b     = d_in[13];
    const void* a_rel   = d_in[14];
    const void* m_rel   = d_in[15];
    const void* p_rel   = d_in[16];
    const void* a_lin_w = d_in[17];
    const void* a_lin_b = d_in[18];
    const void* skip    = d_in[19];

    // -------- workspace layout --------
    char* p = (char*)d_ws;
    auto falloc = [&](size_t n) { float* r = (float*)p; p += n * sizeof(float); return r; };
    float* bias_lin = falloc(768);       // [lin_a_b | lin_b_b | a_lin_b(512)]
    float* b_kqv    = falloc(4 * 384);
    auto halloc = [&](size_t n) { bf16* r = (bf16*)p; p += n * sizeof(bf16); return r; };
    bf16* x_a_bf   = halloc((size_t)NAn * 64);
    bf16* x_b_bf   = halloc((size_t)NBn * 32);
    bf16* xa_bf    = halloc((size_t)NAn * Cc);
    bf16* xb_bf    = halloc((size_t)NBn * Cc);
    bf16* kqv_a    = halloc((size_t)NAn * 384);
    bf16* kqv_b    = halloc((size_t)NBn * 384);
    bf16* wt_lin_a = halloc(128 * 64);
    bf16* wt_lin_b = halloc(128 * 32);
    bf16* wt_kqv   = halloc(4 * 384 * 128);
    bf16* wt_alin  = halloc(4 * 128 * 128);
    auto ialloc = [&](size_t n) { int* r = (int*)p; p += n * sizeof(int); return r; };
    int* dflag     = ialloc(4);
    int* rowptr_ab = ialloc(NBn + 1);
    int* rowptr_ba = ialloc(NAn + 1);
    int* deg_ab    = ialloc(NBn);       // deg_ab/deg_ba adjacent -> zeroed by k_setup
    int* deg_ba    = ialloc(NAn);
    int* cursor_ab = ialloc(NBn);
    int* cursor_ba = ialloc(NAn);
    int* bsum_ab   = ialloc(256);
    int* bsum_ba   = ialloc(256);
    int* csr_ab    = ialloc(NEe);
    int* csr_ba    = ialloc(NEe);

    // -------- dtype detection --------
    k_detect<<<1, 256, 0, stream>>>((const u16*)x_a, 8192, dflag);

    // -------- merged setup: weight prep + deg zeroing + x convert (1 launch) --------
    k_setup<<<1971, 384, 0, stream>>>(lin_a_w, lin_a_b, lin_b_w, lin_b_b, a_lin_w, a_lin_b,
                                      k_w, k_b, q_w, q_b, v_w, v_b, a_rel, m_rel, p_rel,
                                      x_a, x_b,
                                      bias_lin, wt_lin_a, wt_lin_b, wt_alin, wt_kqv, b_kqv,
                                      x_a_bf, x_b_bf, deg_ab, dflag);

    // -------- CSR build, both directions --------
    dim3 eg((NEe + 255) / 256, 2);
    k_hist<<<eg, 256, 0, stream>>>(edge_ab + NEe, edge_ba + NEe, deg_ab, deg_ba);
    int nblk = (NBn + 255) / 256; // 157
    k_scanA<<<dim3(nblk, 2), 256, 0, stream>>>(deg_ab, deg_ba, rowptr_ab, rowptr_ba,
                                               bsum_ab, bsum_ba, NBn);
    k_scanB<<<2, 256, 0, stream>>>(bsum_ab, bsum_ba, nblk);
    k_scanC<<<dim3(nblk, 2), 256, 0, stream>>>(rowptr_ab, rowptr_ba, bsum_ab, bsum_ba,
                                               cursor_ab, cursor_ba, NBn);
    k_scatter<<<eg, 256, 0, stream>>>(edge_ab, edge_ba, cursor_ab, cursor_ba, csr_ab, csr_ba);

    // -------- input linears + relu (LDS-staged) --------
    k_mmL<64, 1><<<dim3(NAn / 64, 1, 1), 256, 0, stream>>>(
        x_a_bf, x_a_bf, 64, wt_lin_a, wt_lin_a, bias_lin, bias_lin,
        xa_bf, xa_bf, 128, nullptr, nullptr, nullptr, 0, 0, nullptr, dflag);
    k_mmL<32, 1><<<dim3(NBn / 64, 1, 1), 256, 0, stream>>>(
        x_b_bf, x_b_bf, 32, wt_lin_b, wt_lin_b, bias_lin + 128, bias_lin + 128,
        xb_bf, xb_bf, 128, nullptr, nullptr, nullptr, 0, 0, nullptr, dflag);

    // -------- layers --------
    for (int l = 0; l < Ll; ++l) {
        int lt0 = l * 2 + 0, lt1 = l * 2 + 1;
        // kqv: LDS-staged, grid (625, 3, 2)
        k_mmL<128, 0><<<dim3(NAn / 64, 3, 2), 256, 0, stream>>>(
            xa_bf, xb_bf, 128,
            wt_kqv + (size_t)lt0 * 384 * 128, wt_kqv + (size_t)lt1 * 384 * 128,
            b_kqv + (size_t)lt0 * 384, b_kqv + (size_t)lt1 * 384,
            kqv_a, kqv_b, 384, nullptr, nullptr, nullptr, 0, 0, nullptr, dflag);
        int nblk0 = NBn / 8; // 5000 blocks per direction, 8 nodes/block
        k_edge<<<nblk0 + NAn / 8, 256, 0, stream>>>(
            kqv_a, kqv_b, rowptr_ab, csr_ab,
            kqv_b, kqv_a, rowptr_ba, csr_ba, nblk0);
        // a_lin + skip blend; final layer writes d_out directly (adaptive dtype)
        if (l == Ll - 1) {
            k_mmL<128, 2, 1><<<dim3(NAn / 64, 1, 2), 256, 0, stream>>>(
                kqv_a + 256, kqv_b + 256, 384,
                wt_alin + (size_t)lt0 * 128 * 128, wt_alin + (size_t)lt1 * 128 * 128,
                bias_lin + 256 + (size_t)lt0 * 128, bias_lin + 256 + (size_t)lt1 * 128,
                nullptr, nullptr, 128, xa_bf, xb_bf, skip, lt0, lt1, d_out, dflag);
        } else {
            k_mmL<128, 2><<<dim3(NAn / 64, 1, 2), 256, 0, stream>>>(
                kqv_a + 256, kqv_b + 256, 384,
                wt_alin + (size_t)lt0 * 128 * 128, wt_alin + (size_t)lt1 * 128 * 128,
                bias_lin + 256 + (size_t)lt0 * 128, bias_lin + 256 + (size_t)lt1 * 128,
                xa_bf, xb_bf, 128, xa_bf, xb_bf, skip, lt0, lt1, nullptr, dflag);
        }
    }
}